// Round 17
// baseline (357.847 us; speedup 1.0000x reference)
//
#include <hip/hip_runtime.h>

#define N_NODES 10000
#define N_EDGES 160000
#define HID 128
#define NG 100
#define NF 64
#define NIO 4096     // NF*NF (w2 row stride)
#define NJ 8192      // permuted columns: o(64) x k(128), o-major
#define M_PAD 10240  // padded x rows

// merged-prep block ranges
#define PREP_EA 10000                  // eaperm: N_EDGES/16
#define PREP_LIN0 (PREP_EA + 2500)     // lin0: N_NODES/4
#define PREP_WPT (PREP_LIN0 + 2112)    // wpt: (HID*HID + NJ*NF)/256

typedef short bf16x8 __attribute__((ext_vector_type(8)));
typedef float f32x4 __attribute__((ext_vector_type(4)));

__device__ __forceinline__ unsigned short f2b(float f) {
    unsigned int u = __float_as_uint(f);
    u += 0x7fffu + ((u >> 16) & 1u);  // RNE
    return (unsigned short)(u >> 16);
}
__device__ __forceinline__ float b2f(unsigned short s) { return __uint_as_float((unsigned int)s << 16); }

// fragment-major index: element (row, k) of a K=64 operand, panel stride 1024
__device__ __forceinline__ long fidx64(int row, int k) {
    return (long)(row >> 4) * 1024 + (k >> 5) * 512 + ((((k >> 3) & 3) * 16 + (row & 15))) * 8 + (k & 7);
}
// K=128 operand, panel stride 2048
__device__ __forceinline__ long fidx128(int row, int k) {
    return (long)(row >> 4) * 2048 + (k >> 5) * 512 + ((((k >> 3) & 3) * 16 + (row & 15))) * 8 + (k & 7);
}

// ---------------- histograms (dst-degree for mean; src-count for CSR) ----------------
__global__ void hist_kernel(const int* __restrict__ src, const int* __restrict__ dst,
                            float* __restrict__ deg, int* __restrict__ cnt) {
    int e = blockIdx.x * 256 + threadIdx.x;
    if (e < N_EDGES) {
        atomicAdd(&deg[dst[e]], 1.0f);
        atomicAdd(&cnt[src[e]], 1);
    }
}

// ---------------- single-pass scan: rowptr = excl-prefix(cnt); invd = 1/max(deg,1) ----------------
#define SCAN_C 40  // 256 threads x 40 = 10240 >= N_NODES
__global__ void scan_kernel(const int* __restrict__ cnt, const float* __restrict__ deg,
                            int* __restrict__ rowptr, float* __restrict__ invd) {
    __shared__ int wsum[4];
    int t = threadIdx.x, wv = t >> 6, l = t & 63;
    int base_i = t * SCAN_C;
    int loc[SCAN_C];
    int sum = 0;
#pragma unroll
    for (int j = 0; j < SCAN_C; ++j) {
        int g = base_i + j;
        int v = (g < N_NODES) ? cnt[g] : 0;
        loc[j] = sum;  // exclusive prefix within thread
        sum += v;
    }
    int incl = sum;
    for (int off = 1; off < 64; off <<= 1) {
        int v = __shfl_up(incl, off);
        if (l >= off) incl += v;
    }
    if (l == 63) wsum[wv] = incl;
    __syncthreads();
    int wbase = 0;
#pragma unroll
    for (int w = 0; w < 4; ++w) wbase += (w < wv) ? wsum[w] : 0;
    int tbase = wbase + incl - sum;  // exclusive across block
#pragma unroll
    for (int j = 0; j < SCAN_C; ++j) {
        int g = base_i + j;
        if (g <= N_NODES) rowptr[g] = tbase + loc[j];
        if (g < N_NODES) invd[g] = 1.0f / fmaxf(deg[g], 1.0f);
    }
}

// ---------------- scatter: edgeOf[rankS], dstp[rankS] ----------------
__global__ void scatter_kernel(const int* __restrict__ src, const int* __restrict__ dst,
                               const int* __restrict__ rowptr, int* __restrict__ fill,
                               int* __restrict__ edgeOf, int* __restrict__ dstp) {
    int e = blockIdx.x * 256 + threadIdx.x;
    if (e < N_EDGES) {
        int s = src[e];
        int r = rowptr[s] + atomicAdd(&fill[s], 1);
        edgeOf[r] = e;
        dstp[r] = dst[e];
    }
}

// ---------------- merged prep: eaperm (LDS-staged) | lin0(+xb2) | weight permutes ----------------
__global__ void prep_kernel(const float* __restrict__ ea, const int* __restrict__ edgeOf,
                            unsigned short* __restrict__ eah,
                            const float* __restrict__ h, const float* __restrict__ lw,
                            const float* __restrict__ lb, const float* __restrict__ b2,
                            float* __restrict__ x, unsigned short* __restrict__ xh,
                            float* __restrict__ xb2,
                            const float* __restrict__ w1, const float* __restrict__ w2,
                            unsigned short* __restrict__ w1h, unsigned short* __restrict__ w2h) {
    int bid = blockIdx.x;
    if (bid < PREP_EA) {
        // ---- eaperm: coalesced row loads -> LDS -> fragment-major coalesced writes ----
        __shared__ float rows[16][132];  // pad 132: bank stride 4 -> 2-way (free)
        __shared__ int eids[16];
        int t = threadIdx.x;
        if (t < 16) eids[t] = edgeOf[(long)bid * 16 + t];
        __syncthreads();
#pragma unroll
        for (int pass = 0; pass < 8; ++pass) {
            int r = pass * 2 + (t >> 7);      // 2 rows per pass
            int c = t & 127;                  // 128 consecutive lanes read one row
            long e = eids[r];
            rows[r][c] = (c < NG) ? ea[e * NG + c] : 0.0f;
        }
        __syncthreads();
        int r15 = t & 15, ksl = t >> 4;
        int ks = ksl >> 2, lk = ksl & 3;
        int c0 = ks * 32 + lk * 8;
        unsigned int uh[4];
#pragma unroll
        for (int p = 0; p < 4; ++p) {
            float v0 = rows[r15][c0 + 2 * p];
            float v1 = rows[r15][c0 + 2 * p + 1];
            uh[p] = ((unsigned int)f2b(v1) << 16) | f2b(v0);
        }
        long idx = (long)bid * 2048 + ks * 512 + (lk * 16 + r15) * 8;
        *(uint4*)(eah + idx) = make_uint4(uh[0], uh[1], uh[2], uh[3]);
    } else if (bid < PREP_LIN0) {
        // ---- lin0: x0 = relu(h @ lin0_w + b); f32 + xh frag mirror + fused xb2 ----
        int wv = threadIdx.x >> 6, l = threadIdx.x & 63;
        int n = (bid - PREP_EA) * 4 + wv;
        float h0 = h[n * HID + l];
        float h1 = h[n * HID + 64 + l];
        float acc = lb[l];
#pragma unroll
        for (int i = 0; i < 64; ++i) {
            acc += __shfl(h0, i) * lw[i * NF + l];
            acc += __shfl(h1, i) * lw[(64 + i) * NF + l];
        }
        float v = fmaxf(acc, 0.0f);
        x[n * NF + l] = v;
        xh[fidx64(n, l)] = f2b(v);
        float xb = 0.0f;
#pragma unroll
        for (int i = 0; i < 64; ++i) xb += __shfl(v, i) * b2[i * 64 + l];
        xb2[n * NF + l] = xb;
    } else {
        // ---- weight permutes: w1 (first 16384 ids) + w2 ----
        int id = (bid - PREP_LIN0) * 256 + threadIdx.x;
        if (id < HID * HID) {
            int k = id & 127, c = id >> 7;
            float v = (k < NG) ? w1[k * HID + c] : 0.0f;
            w1h[fidx128(c, k)] = f2b(v);
        } else {
            int id2 = id - HID * HID;  // id2 = j*64 + i
            int i = id2 & 63, j = id2 >> 6;
            int o = j >> 7, k = j & 127;  // j = o*128 + k
            w2h[fidx64(j, i)] = f2b(w2[k * NIO + i * 64 + o]);
        }
    }
}

// ---------------- hgemm: hidp = relu(eap @ w1 + b1), single-pass bf16 ----------------
__launch_bounds__(256)
__global__ void hgemm_kernel(const unsigned short* __restrict__ eah,
                             const unsigned short* __restrict__ w1h,
                             const float* __restrict__ b1, unsigned short* __restrict__ hidp) {
    __shared__ float stg[4][1056];
    const int tid = threadIdx.x, wv = tid >> 6, l = tid & 63;
    const long grow = (long)blockIdx.x * 128;
    const int wr = (wv >> 1) * 64, wc = (wv & 1) * 64;
    const long apan0 = (grow >> 4) + (wr >> 4);
    const long bpan0 = (wc >> 4);

    f32x4 acc[4][4] = {};
#pragma unroll
    for (int ks = 0; ks < 4; ++ks) {
        bf16x8 a[4], b[4];
#pragma unroll
        for (int m = 0; m < 4; ++m)
            a[m] = *(const bf16x8*)(eah + (apan0 + m) * 2048 + ks * 512 + (long)l * 8);
#pragma unroll
        for (int n = 0; n < 4; ++n)
            b[n] = *(const bf16x8*)(w1h + (bpan0 + n) * 2048 + ks * 512 + (long)l * 8);
#pragma unroll
        for (int m = 0; m < 4; ++m)
#pragma unroll
            for (int n = 0; n < 4; ++n)
                acc[m][n] = __builtin_amdgcn_mfma_f32_16x16x32_bf16(a[m], b[n], acc[m][n], 0, 0, 0);
    }

    float* s = stg[wv];
    int r8 = l >> 3, cg = l & 7;
#pragma unroll
    for (int m = 0; m < 4; ++m) {
#pragma unroll
        for (int n = 0; n < 4; ++n)
#pragma unroll
            for (int q = 0; q < 4; ++q)
                s[((l >> 4) * 4 + q) * 66 + n * 16 + (l & 15)] = acc[m][n][q];
#pragma unroll
        for (int it = 0; it < 2; ++it) {
            int row = it * 8 + r8;
            const float* sr = s + row * 66 + cg * 8;
            int colbase = wc + cg * 8;
            unsigned int u[4];
#pragma unroll
            for (int p = 0; p < 4; ++p) {
                float f0 = fmaxf(sr[2 * p] + b1[colbase + 2 * p], 0.0f);
                float f1 = fmaxf(sr[2 * p + 1] + b1[colbase + 2 * p + 1], 0.0f);
                u[p] = ((unsigned int)f2b(f1) << 16) | f2b(f0);
            }
            long R = grow + wr + m * 16 + row;
            *(uint4*)(hidp + R * HID + colbase) = make_uint4(u[0], u[1], u[2], u[3]);
        }
    }
}

// ---------------- ygemm: single-pass bf16, 2 col-tiles per block (A-frag reuse) ----------------
__launch_bounds__(256)
__global__ void ygemm_kernel(const unsigned short* __restrict__ xh,
                             const unsigned short* __restrict__ wh,
                             unsigned short* __restrict__ y, int n0) {
    __shared__ float stg[4][1056];
    const int tid = threadIdx.x, wv = tid >> 6, l = tid & 63;
    const int grow = blockIdx.x * 128;
    const int col0base = blockIdx.y * 256;  // 2 x 128-col tiles
    const int wr = (wv >> 1) * 64, wc = (wv & 1) * 64;
    const long apan0 = ((n0 + grow + wr) >> 4);
    const int r8 = l >> 3, cg = l & 7;

    // A-fragments loaded once, reused across both col-tiles
    bf16x8 a[2][4];
#pragma unroll
    for (int ks = 0; ks < 2; ++ks)
#pragma unroll
        for (int m = 0; m < 4; ++m)
            a[ks][m] = *(const bf16x8*)(xh + (apan0 + m) * 1024 + ks * 512 + (long)l * 8);

    for (int ct = 0; ct < 2; ++ct) {
        const int col0 = col0base + ct * 128;
        const long bpan0 = ((col0 + wc) >> 4);
        f32x4 acc[4][4] = {};
#pragma unroll
        for (int ks = 0; ks < 2; ++ks) {
            bf16x8 b[4];
#pragma unroll
            for (int n = 0; n < 4; ++n)
                b[n] = *(const bf16x8*)(wh + (bpan0 + n) * 1024 + ks * 512 + (long)l * 8);
#pragma unroll
            for (int m = 0; m < 4; ++m)
#pragma unroll
                for (int n = 0; n < 4; ++n)
                    acc[m][n] = __builtin_amdgcn_mfma_f32_16x16x32_bf16(a[ks][m], b[n], acc[m][n], 0, 0, 0);
        }

        float* s = stg[wv];
#pragma unroll
        for (int m = 0; m < 4; ++m) {
#pragma unroll
            for (int n = 0; n < 4; ++n)
#pragma unroll
                for (int q = 0; q < 4; ++q)
                    s[((l >> 4) * 4 + q) * 66 + n * 16 + (l & 15)] = acc[m][n][q];
            // wave-private staging: same-wave ds_write -> ds_read ordered via lgkmcnt
#pragma unroll
            for (int it = 0; it < 2; ++it) {
                int row = it * 8 + r8;
                const float* sr = s + row * 66 + cg * 8;
                unsigned int u[4];
#pragma unroll
                for (int p = 0; p < 4; ++p)
                    u[p] = ((unsigned int)f2b(sr[2 * p + 1]) << 16) | f2b(sr[2 * p]);
                long R = grow + wr + m * 16 + row;
                *(uint4*)(y + R * NJ + col0 + wc + cg * 8) = make_uint4(u[0], u[1], u[2], u[3]);
            }
        }
    }
}

// ---------------- matvec: ONE WAVE PER NODE (all 64 o), atomic scatter into agg ----------------
__global__ void matvec_mfma_kernel(const unsigned short* __restrict__ y,
                                   const unsigned short* __restrict__ hidp,
                                   const int* __restrict__ rowptr, const int* __restrict__ dstp,
                                   const float* __restrict__ xb2, float* __restrict__ agg,
                                   int n0, int n1) {
    int wv = threadIdx.x >> 6, l = threadIdx.x & 63;
    int s = n0 + blockIdx.x * 4 + wv;
    if (s >= n1) return;
    int r0 = rowptr[s], r1 = rowptr[s + 1];
    if (r0 == r1) return;
    int lc = l & 15, lk = l >> 4;

    // B-fragments for all 4 o-groups: y[s] is o-major [o][k], k contiguous
    const unsigned short* Ys = y + (long)(s - n0) * NJ;
    bf16x8 b[4][4];
    float xb2v[4];
#pragma unroll
    for (int og = 0; og < 4; ++og) {
        const unsigned short* Yo = Ys + (og * 16 + lc) * HID + lk * 8;
#pragma unroll
        for (int ks = 0; ks < 4; ++ks) b[og][ks] = *(const bf16x8*)(Yo + ks * 32);
        xb2v[og] = xb2[(long)s * NF + og * 16 + lc];
    }

    for (int mt = r0; mt < r1; mt += 16) {
        const unsigned short* Hs = hidp + (long)(mt + lc) * HID + lk * 8;
        bf16x8 a[4];
#pragma unroll
        for (int ks = 0; ks < 4; ++ks) a[ks] = *(const bf16x8*)(Hs + ks * 32);  // shared across og
        f32x4 acc[4] = {};
#pragma unroll
        for (int og = 0; og < 4; ++og)
#pragma unroll
            for (int ks = 0; ks < 4; ++ks)
                acc[og] = __builtin_amdgcn_mfma_f32_16x16x32_bf16(a[ks], b[og][ks], acc[og], 0, 0, 0);
#pragma unroll
        for (int q = 0; q < 4; ++q) {
            int rank = mt + lk * 4 + q;
            if (rank < r1) {
                long base = (long)dstp[rank] * NF;
#pragma unroll
                for (int og = 0; og < 4; ++og)
                    atomicAdd(&agg[base + og * 16 + lc], acc[og][q] + xb2v[og]);
            }
        }
    }
}

// ---------------- combine: agg*inv_deg + x @ root_w + conv_b; zeroes agg for next conv ----------------
__global__ void combine_kernel(const float* __restrict__ x, float* __restrict__ agg,
                               const float* __restrict__ invd, const float* __restrict__ rw,
                               const float* __restrict__ cb, const float* __restrict__ b2,
                               float* __restrict__ xo, unsigned short* __restrict__ xh,
                               float* __restrict__ xb2) {
    int wv = threadIdx.x >> 6, l = threadIdx.x & 63;
    int n = blockIdx.x * 4 + wv;
    float xv = x[n * NF + l];
    float acc = cb[l];
#pragma unroll
    for (int i = 0; i < 64; ++i) acc += __shfl(xv, i) * rw[i * NF + l];
    float av = agg[n * NF + l];
    agg[n * NF + l] = 0.0f;  // re-zero for next conv (replay-safe: prep memset covers conv0)
    float v = av * invd[n] + acc;
    xo[n * NF + l] = v;
    if (xh) {
        xh[fidx64(n, l)] = f2b(v);
        float xb = 0.0f;
#pragma unroll
        for (int i = 0; i < 64; ++i) xb += __shfl(v, i) * b2[i * 64 + l];
        xb2[n * NF + l] = xb;
    }
}

extern "C" void kernel_launch(void* const* d_in, const int* in_sizes, int n_in,
                              void* d_out, int out_size, void* d_ws, size_t ws_size,
                              hipStream_t stream) {
    const float* h = (const float*)d_in[0];
    const int* ei = (const int*)d_in[1];
    const float* ea = (const float*)d_in[3];
    const float* lin0_w = (const float*)d_in[5];
    const float* lin0_b = (const float*)d_in[6];
    const float* nn_w1 = (const float*)d_in[7];
    const float* nn_b1 = (const float*)d_in[8];
    const float* nn_w2 = (const float*)d_in[9];
    const float* nn_b2 = (const float*)d_in[10];
    const float* root_w = (const float*)d_in[11];
    const float* conv_b = (const float*)d_in[12];
    const int* srcIdx = ei;
    const int* dstIdx = ei + N_EDGES;

    // ---- tier selection: start at nc=2 so the y chunk (~84MB) stays LLC-resident ----
    const size_t eaBytes = (size_t)N_EDGES * HID * 2;  // eah (aliased with y region)
    const size_t fixed =
        (size_t)(N_EDGES + 16) * HID * 2 +  // hidp
        (size_t)NJ * NF * 2 +               // w2h
        (size_t)HID * HID * 2 +             // w1h
        (size_t)M_PAD * NF * 2 +            // xh mirror
        (size_t)N_NODES * NF * 4 * 4 +      // xA, xB, agg, xb2
        3 * 40192 +                         // deg | cnt | fill block
        (size_t)N_NODES * 4 +               // invd
        (size_t)(N_NODES + 1) * 4 +         // rowptr
        (size_t)N_EDGES * 4 * 2 +           // edgeOf, dstp
        32768;
    int nc = 0, CSn = 0;
    size_t region_bytes = 0;
    for (int c = 2; c <= 16; c *= 2) {
        int csn = (((N_NODES + c - 1) / c) + 127) & ~127;
        size_t rb = (size_t)csn * NJ * 2;
        if (rb < eaBytes) rb = eaBytes;
        if (fixed + rb <= ws_size) { nc = c; CSn = csn; region_bytes = rb; break; }
    }
    if (nc == 0) {
        hipMemsetAsync(d_out, 0, (size_t)out_size * 4, stream);
        return;
    }

    char* ws = (char*)d_ws;
    size_t off = 0;
    auto alloc = [&](size_t bytes) {
        char* p = ws + off;
        off += (bytes + 255) & ~(size_t)255;
        return p;
    };
    unsigned short* region = (unsigned short*)alloc(region_bytes);
    unsigned short* y = region;
    unsigned short* eah = region;  // prep only (consumed by hgemm before first ygemm)
    unsigned short* hidp = (unsigned short*)alloc((size_t)(N_EDGES + 16) * HID * 2);
    unsigned short* w2h = (unsigned short*)alloc((size_t)NJ * NF * 2);
    unsigned short* w1h = (unsigned short*)alloc((size_t)HID * HID * 2);
    unsigned short* xh = (unsigned short*)alloc((size_t)M_PAD * NF * 2);
    float* xA = (float*)alloc((size_t)N_NODES * NF * 4);
    float* xB = (float*)alloc((size_t)N_NODES * NF * 4);
    float* agg = (float*)alloc((size_t)N_NODES * NF * 4);
    float* xb2 = (float*)alloc((size_t)N_NODES * NF * 4);
    char* degblk = alloc(3 * 40192);  // deg | cnt | fill (one memset)
    float* deg = (float*)degblk;
    int* cnt = (int*)(degblk + 40192);
    int* fill = (int*)(degblk + 2 * 40192);
    float* invd = (float*)alloc((size_t)N_NODES * 4);
    int* rowptr = (int*)alloc((size_t)(N_NODES + 1) * 4);
    int* edgeOf = (int*)alloc((size_t)N_EDGES * 4);
    int* dstp = (int*)alloc((size_t)N_EDGES * 4);

    // ---- prep: CSR by src + merged features/weights + hidden ----
    hipMemsetAsync(degblk, 0, 3 * 40192, stream);
    hipMemsetAsync(agg, 0, (size_t)N_NODES * NF * 4, stream);  // conv0's agg init
    hist_kernel<<<(N_EDGES + 255) / 256, 256, 0, stream>>>(srcIdx, dstIdx, deg, cnt);
    scan_kernel<<<1, 256, 0, stream>>>(cnt, deg, rowptr, invd);
    scatter_kernel<<<(N_EDGES + 255) / 256, 256, 0, stream>>>(srcIdx, dstIdx, rowptr, fill, edgeOf, dstp);
    prep_kernel<<<PREP_WPT, 256, 0, stream>>>(ea, edgeOf, eah,
                                              h, lin0_w, lin0_b, nn_b2, xA, xh, xb2,
                                              nn_w1, nn_w2, w1h, w2h);
    hgemm_kernel<<<N_EDGES / 128, 256, 0, stream>>>(eah, w1h, nn_b1, hidp);  // consumes ea region

    // ---- two conv applications (shared weights) ----
    for (int conv = 0; conv < 2; ++conv) {
        const float* xin = conv ? xB : xA;
        float* xout = conv ? (float*)d_out : xB;
        unsigned short* mh = conv ? nullptr : xh;

        for (int c = 0; c < nc; ++c) {
            int n0 = c * CSn;
            int n1 = n0 + CSn; if (n1 > N_NODES) n1 = N_NODES;
            if (n0 >= N_NODES) break;
            int gx = (n1 - n0 + 127) / 128;
            ygemm_kernel<<<dim3(gx, NJ / 256), 256, 0, stream>>>(xh, w2h, y, n0);
            matvec_mfma_kernel<<<(n1 - n0 + 3) / 4, 256, 0, stream>>>(y, hidp, rowptr, dstp,
                                                                      xb2, agg, n0, n1);
        }
        // combine reads agg and re-zeroes it for the next conv
        combine_kernel<<<N_NODES / 4, 256, 0, stream>>>(xin, agg, invd, root_w, conv_b, nn_b2,
                                                        xout, mh, xb2);
    }
}

// Round 18
// 342.798 us; speedup vs baseline: 1.0439x; 1.0439x over previous
//
#include <hip/hip_runtime.h>

#define N_NODES 10000
#define N_EDGES 160000
#define HID 128
#define NG 100
#define NF 64
#define NIO 4096     // NF*NF (w2 row stride)
#define NJ 8192      // permuted columns: o(64) x k(128), o-major
#define M_PAD 10240  // padded x rows

// merged-prep block ranges
#define PREP_EA 5000                   // eaperm: N_EDGES/32 (32 ranks per block)
#define PREP_LIN0 (PREP_EA + 2500)     // lin0: N_NODES/4
#define PREP_WPT (PREP_LIN0 + 2112)    // wpt: (HID*HID + NJ*NF)/256

typedef short bf16x8 __attribute__((ext_vector_type(8)));
typedef float f32x4 __attribute__((ext_vector_type(4)));

__device__ __forceinline__ unsigned short f2b(float f) {
    unsigned int u = __float_as_uint(f);
    u += 0x7fffu + ((u >> 16) & 1u);  // RNE
    return (unsigned short)(u >> 16);
}
__device__ __forceinline__ float b2f(unsigned short s) { return __uint_as_float((unsigned int)s << 16); }

// fragment-major index: element (row, k) of a K=64 operand, panel stride 1024
__device__ __forceinline__ long fidx64(int row, int k) {
    return (long)(row >> 4) * 1024 + (k >> 5) * 512 + ((((k >> 3) & 3) * 16 + (row & 15))) * 8 + (k & 7);
}
// K=128 operand, panel stride 2048
__device__ __forceinline__ long fidx128(int row, int k) {
    return (long)(row >> 4) * 2048 + (k >> 5) * 512 + ((((k >> 3) & 3) * 16 + (row & 15))) * 8 + (k & 7);
}

// ---------------- histograms (dst-degree for mean; src-count for CSR) ----------------
__global__ void hist_kernel(const int* __restrict__ src, const int* __restrict__ dst,
                            float* __restrict__ deg, int* __restrict__ cnt) {
    int e = blockIdx.x * 256 + threadIdx.x;
    if (e < N_EDGES) {
        atomicAdd(&deg[dst[e]], 1.0f);
        atomicAdd(&cnt[src[e]], 1);
    }
}

// ---------------- single-pass scan: rowptr = excl-prefix(cnt); invd = 1/max(deg,1) ----------------
#define SCAN_C 40  // 256 threads x 40 = 10240 >= N_NODES
__global__ void scan_kernel(const int* __restrict__ cnt, const float* __restrict__ deg,
                            int* __restrict__ rowptr, float* __restrict__ invd) {
    __shared__ int wsum[4];
    int t = threadIdx.x, wv = t >> 6, l = t & 63;
    int base_i = t * SCAN_C;
    int loc[SCAN_C];
    int sum = 0;
#pragma unroll
    for (int j = 0; j < SCAN_C; ++j) {
        int g = base_i + j;
        int v = (g < N_NODES) ? cnt[g] : 0;
        loc[j] = sum;  // exclusive prefix within thread
        sum += v;
    }
    int incl = sum;
    for (int off = 1; off < 64; off <<= 1) {
        int v = __shfl_up(incl, off);
        if (l >= off) incl += v;
    }
    if (l == 63) wsum[wv] = incl;
    __syncthreads();
    int wbase = 0;
#pragma unroll
    for (int w = 0; w < 4; ++w) wbase += (w < wv) ? wsum[w] : 0;
    int tbase = wbase + incl - sum;  // exclusive across block
#pragma unroll
    for (int j = 0; j < SCAN_C; ++j) {
        int g = base_i + j;
        if (g <= N_NODES) rowptr[g] = tbase + loc[j];
        if (g < N_NODES) invd[g] = 1.0f / fmaxf(deg[g], 1.0f);
    }
}

// ---------------- scatter: edgeOf[rankS], dstp[rankS] ----------------
__global__ void scatter_kernel(const int* __restrict__ src, const int* __restrict__ dst,
                               const int* __restrict__ rowptr, int* __restrict__ fill,
                               int* __restrict__ edgeOf, int* __restrict__ dstp) {
    int e = blockIdx.x * 256 + threadIdx.x;
    if (e < N_EDGES) {
        int s = src[e];
        int r = rowptr[s] + atomicAdd(&fill[s], 1);
        edgeOf[r] = e;
        dstp[r] = dst[e];
    }
}

// ---------------- merged prep: eaperm (32 ranks/blk, float4) | lin0(+xb2) | weight permutes ----------------
__global__ void prep_kernel(const float* __restrict__ ea, const int* __restrict__ edgeOf,
                            unsigned short* __restrict__ eah,
                            const float* __restrict__ h, const float* __restrict__ lw,
                            const float* __restrict__ lb, const float* __restrict__ b2,
                            float* __restrict__ x, unsigned short* __restrict__ xh,
                            float* __restrict__ xb2,
                            const float* __restrict__ w1, const float* __restrict__ w2,
                            unsigned short* __restrict__ w1h, unsigned short* __restrict__ w2h) {
    int bid = blockIdx.x;
    if (bid < PREP_EA) {
        // ---- eaperm: 32 ranks per block, 2x unrolled, float4 loads (64B/thread in flight) ----
        int t = threadIdx.x;
        int r15 = t & 15, ksl = t >> 4;
        int ks = ksl >> 2, lk = ksl & 3;
        int c0 = ks * 32 + lk * 8;
        f32x4 ld0[2], ld1[2];
        long rk[2];
#pragma unroll
        for (int rr = 0; rr < 2; ++rr) {
            rk[rr] = (long)bid * 32 + rr * 16 + r15;
            long e = edgeOf[rk[rr]];
            const float* row = ea + e * NG;
            if (c0 < 96) {
                ld0[rr] = *(const f32x4*)(row + c0);
                ld1[rr] = *(const f32x4*)(row + c0 + 4);
            } else {  // c0 == 96: elems 96..99 valid, 100..127 zero-pad
                ld0[rr] = *(const f32x4*)(row + 96);
                ld1[rr] = f32x4{0.0f, 0.0f, 0.0f, 0.0f};
            }
        }
#pragma unroll
        for (int rr = 0; rr < 2; ++rr) {
            unsigned int uh[4];
#pragma unroll
            for (int p = 0; p < 2; ++p)
                uh[p] = ((unsigned int)f2b(ld0[rr][2 * p + 1]) << 16) | f2b(ld0[rr][2 * p]);
#pragma unroll
            for (int p = 0; p < 2; ++p)
                uh[2 + p] = ((unsigned int)f2b(ld1[rr][2 * p + 1]) << 16) | f2b(ld1[rr][2 * p]);
            long idx = (long)((bid << 1) + rr) * 2048 + ks * 512 + (lk * 16 + r15) * 8;
            *(uint4*)(eah + idx) = make_uint4(uh[0], uh[1], uh[2], uh[3]);
        }
    } else if (bid < PREP_LIN0) {
        // ---- lin0: x0 = relu(h @ lin0_w + b); f32 + xh frag mirror + fused xb2 ----
        int wv = threadIdx.x >> 6, l = threadIdx.x & 63;
        int n = (bid - PREP_EA) * 4 + wv;
        float h0 = h[n * HID + l];
        float h1 = h[n * HID + 64 + l];
        float acc = lb[l];
#pragma unroll
        for (int i = 0; i < 64; ++i) {
            acc += __shfl(h0, i) * lw[i * NF + l];
            acc += __shfl(h1, i) * lw[(64 + i) * NF + l];
        }
        float v = fmaxf(acc, 0.0f);
        x[n * NF + l] = v;
        xh[fidx64(n, l)] = f2b(v);
        float xb = 0.0f;
#pragma unroll
        for (int i = 0; i < 64; ++i) xb += __shfl(v, i) * b2[i * 64 + l];
        xb2[n * NF + l] = xb;
    } else {
        // ---- weight permutes: w1 (first 16384 ids) + w2 ----
        int id = (bid - PREP_LIN0) * 256 + threadIdx.x;
        if (id < HID * HID) {
            int k = id & 127, c = id >> 7;
            float v = (k < NG) ? w1[k * HID + c] : 0.0f;
            w1h[fidx128(c, k)] = f2b(v);
        } else {
            int id2 = id - HID * HID;  // id2 = j*64 + i
            int i = id2 & 63, j = id2 >> 6;
            int o = j >> 7, k = j & 127;  // j = o*128 + k
            w2h[fidx64(j, i)] = f2b(w2[k * NIO + i * 64 + o]);
        }
    }
}

// ---------------- hgemm: hidp = relu(eap @ w1 + b1), single-pass bf16 ----------------
__launch_bounds__(256)
__global__ void hgemm_kernel(const unsigned short* __restrict__ eah,
                             const unsigned short* __restrict__ w1h,
                             const float* __restrict__ b1, unsigned short* __restrict__ hidp) {
    __shared__ float stg[4][1056];
    const int tid = threadIdx.x, wv = tid >> 6, l = tid & 63;
    const long grow = (long)blockIdx.x * 128;
    const int wr = (wv >> 1) * 64, wc = (wv & 1) * 64;
    const long apan0 = (grow >> 4) + (wr >> 4);
    const long bpan0 = (wc >> 4);

    f32x4 acc[4][4] = {};
#pragma unroll
    for (int ks = 0; ks < 4; ++ks) {
        bf16x8 a[4], b[4];
#pragma unroll
        for (int m = 0; m < 4; ++m)
            a[m] = *(const bf16x8*)(eah + (apan0 + m) * 2048 + ks * 512 + (long)l * 8);
#pragma unroll
        for (int n = 0; n < 4; ++n)
            b[n] = *(const bf16x8*)(w1h + (bpan0 + n) * 2048 + ks * 512 + (long)l * 8);
#pragma unroll
        for (int m = 0; m < 4; ++m)
#pragma unroll
            for (int n = 0; n < 4; ++n)
                acc[m][n] = __builtin_amdgcn_mfma_f32_16x16x32_bf16(a[m], b[n], acc[m][n], 0, 0, 0);
    }

    float* s = stg[wv];
    int r8 = l >> 3, cg = l & 7;
#pragma unroll
    for (int m = 0; m < 4; ++m) {
#pragma unroll
        for (int n = 0; n < 4; ++n)
#pragma unroll
            for (int q = 0; q < 4; ++q)
                s[((l >> 4) * 4 + q) * 66 + n * 16 + (l & 15)] = acc[m][n][q];
#pragma unroll
        for (int it = 0; it < 2; ++it) {
            int row = it * 8 + r8;
            const float* sr = s + row * 66 + cg * 8;
            int colbase = wc + cg * 8;
            unsigned int u[4];
#pragma unroll
            for (int p = 0; p < 4; ++p) {
                float f0 = fmaxf(sr[2 * p] + b1[colbase + 2 * p], 0.0f);
                float f1 = fmaxf(sr[2 * p + 1] + b1[colbase + 2 * p + 1], 0.0f);
                u[p] = ((unsigned int)f2b(f1) << 16) | f2b(f0);
            }
            long R = grow + wr + m * 16 + row;
            *(uint4*)(hidp + R * HID + colbase) = make_uint4(u[0], u[1], u[2], u[3]);
        }
    }
}

// ---------------- ygemm: single-pass bf16, 2 col-tiles per block (A-frag reuse) ----------------
__launch_bounds__(256)
__global__ void ygemm_kernel(const unsigned short* __restrict__ xh,
                             const unsigned short* __restrict__ wh,
                             unsigned short* __restrict__ y, int n0) {
    __shared__ float stg[4][1056];
    const int tid = threadIdx.x, wv = tid >> 6, l = tid & 63;
    const int grow = blockIdx.x * 128;
    const int col0base = blockIdx.y * 256;  // 2 x 128-col tiles
    const int wr = (wv >> 1) * 64, wc = (wv & 1) * 64;
    const long apan0 = ((n0 + grow + wr) >> 4);
    const int r8 = l >> 3, cg = l & 7;

    // A-fragments loaded once, reused across both col-tiles
    bf16x8 a[2][4];
#pragma unroll
    for (int ks = 0; ks < 2; ++ks)
#pragma unroll
        for (int m = 0; m < 4; ++m)
            a[ks][m] = *(const bf16x8*)(xh + (apan0 + m) * 1024 + ks * 512 + (long)l * 8);

    for (int ct = 0; ct < 2; ++ct) {
        const int col0 = col0base + ct * 128;
        const long bpan0 = ((col0 + wc) >> 4);
        f32x4 acc[4][4] = {};
#pragma unroll
        for (int ks = 0; ks < 2; ++ks) {
            bf16x8 b[4];
#pragma unroll
            for (int n = 0; n < 4; ++n)
                b[n] = *(const bf16x8*)(wh + (bpan0 + n) * 1024 + ks * 512 + (long)l * 8);
#pragma unroll
            for (int m = 0; m < 4; ++m)
#pragma unroll
                for (int n = 0; n < 4; ++n)
                    acc[m][n] = __builtin_amdgcn_mfma_f32_16x16x32_bf16(a[ks][m], b[n], acc[m][n], 0, 0, 0);
        }

        float* s = stg[wv];
#pragma unroll
        for (int m = 0; m < 4; ++m) {
#pragma unroll
            for (int n = 0; n < 4; ++n)
#pragma unroll
                for (int q = 0; q < 4; ++q)
                    s[((l >> 4) * 4 + q) * 66 + n * 16 + (l & 15)] = acc[m][n][q];
            // wave-private staging: same-wave ds_write -> ds_read ordered via lgkmcnt
#pragma unroll
            for (int it = 0; it < 2; ++it) {
                int row = it * 8 + r8;
                const float* sr = s + row * 66 + cg * 8;
                unsigned int u[4];
#pragma unroll
                for (int p = 0; p < 4; ++p)
                    u[p] = ((unsigned int)f2b(sr[2 * p + 1]) << 16) | f2b(sr[2 * p]);
                long R = grow + wr + m * 16 + row;
                *(uint4*)(y + R * NJ + col0 + wc + cg * 8) = make_uint4(u[0], u[1], u[2], u[3]);
            }
        }
    }
}

// ---------------- matvec: ONE WAVE PER NODE (all 64 o), atomic scatter into agg ----------------
__global__ void matvec_mfma_kernel(const unsigned short* __restrict__ y,
                                   const unsigned short* __restrict__ hidp,
                                   const int* __restrict__ rowptr, const int* __restrict__ dstp,
                                   const float* __restrict__ xb2, float* __restrict__ agg,
                                   int n0, int n1) {
    int wv = threadIdx.x >> 6, l = threadIdx.x & 63;
    int s = n0 + blockIdx.x * 4 + wv;
    if (s >= n1) return;
    int r0 = rowptr[s], r1 = rowptr[s + 1];
    if (r0 == r1) return;
    int lc = l & 15, lk = l >> 4;

    // B-fragments for all 4 o-groups: y[s] is o-major [o][k], k contiguous
    const unsigned short* Ys = y + (long)(s - n0) * NJ;
    bf16x8 b[4][4];
    float xb2v[4];
#pragma unroll
    for (int og = 0; og < 4; ++og) {
        const unsigned short* Yo = Ys + (og * 16 + lc) * HID + lk * 8;
#pragma unroll
        for (int ks = 0; ks < 4; ++ks) b[og][ks] = *(const bf16x8*)(Yo + ks * 32);
        xb2v[og] = xb2[(long)s * NF + og * 16 + lc];
    }

    for (int mt = r0; mt < r1; mt += 16) {
        const unsigned short* Hs = hidp + (long)(mt + lc) * HID + lk * 8;
        bf16x8 a[4];
#pragma unroll
        for (int ks = 0; ks < 4; ++ks) a[ks] = *(const bf16x8*)(Hs + ks * 32);  // shared across og
        f32x4 acc[4] = {};
#pragma unroll
        for (int og = 0; og < 4; ++og)
#pragma unroll
            for (int ks = 0; ks < 4; ++ks)
                acc[og] = __builtin_amdgcn_mfma_f32_16x16x32_bf16(a[ks], b[og][ks], acc[og], 0, 0, 0);
#pragma unroll
        for (int q = 0; q < 4; ++q) {
            int rank = mt + lk * 4 + q;
            if (rank < r1) {
                long base = (long)dstp[rank] * NF;
#pragma unroll
                for (int og = 0; og < 4; ++og)
                    atomicAdd(&agg[base + og * 16 + lc], acc[og][q] + xb2v[og]);
            }
        }
    }
}

// ---------------- combine: agg*inv_deg + x @ root_w + conv_b; zeroes agg for next conv ----------------
__global__ void combine_kernel(const float* __restrict__ x, float* __restrict__ agg,
                               const float* __restrict__ invd, const float* __restrict__ rw,
                               const float* __restrict__ cb, const float* __restrict__ b2,
                               float* __restrict__ xo, unsigned short* __restrict__ xh,
                               float* __restrict__ xb2) {
    int wv = threadIdx.x >> 6, l = threadIdx.x & 63;
    int n = blockIdx.x * 4 + wv;
    float xv = x[n * NF + l];
    float acc = cb[l];
#pragma unroll
    for (int i = 0; i < 64; ++i) acc += __shfl(xv, i) * rw[i * NF + l];
    float av = agg[n * NF + l];
    agg[n * NF + l] = 0.0f;  // re-zero for next conv (replay-safe: prep memset covers conv0)
    float v = av * invd[n] + acc;
    xo[n * NF + l] = v;
    if (xh) {
        xh[fidx64(n, l)] = f2b(v);
        float xb = 0.0f;
#pragma unroll
        for (int i = 0; i < 64; ++i) xb += __shfl(v, i) * b2[i * 64 + l];
        xb2[n * NF + l] = xb;
    }
}

extern "C" void kernel_launch(void* const* d_in, const int* in_sizes, int n_in,
                              void* d_out, int out_size, void* d_ws, size_t ws_size,
                              hipStream_t stream) {
    const float* h = (const float*)d_in[0];
    const int* ei = (const int*)d_in[1];
    const float* ea = (const float*)d_in[3];
    const float* lin0_w = (const float*)d_in[5];
    const float* lin0_b = (const float*)d_in[6];
    const float* nn_w1 = (const float*)d_in[7];
    const float* nn_b1 = (const float*)d_in[8];
    const float* nn_w2 = (const float*)d_in[9];
    const float* nn_b2 = (const float*)d_in[10];
    const float* root_w = (const float*)d_in[11];
    const float* conv_b = (const float*)d_in[12];
    const int* srcIdx = ei;
    const int* dstIdx = ei + N_EDGES;

    // ---- tier selection: start at nc=2 so the y chunk (~84MB) stays LLC-resident ----
    const size_t eaBytes = (size_t)N_EDGES * HID * 2;  // eah (aliased with y region)
    const size_t fixed =
        (size_t)(N_EDGES + 16) * HID * 2 +  // hidp
        (size_t)NJ * NF * 2 +               // w2h
        (size_t)HID * HID * 2 +             // w1h
        (size_t)M_PAD * NF * 2 +            // xh mirror
        (size_t)N_NODES * NF * 4 * 4 +      // xA, xB, agg, xb2
        3 * 40192 +                         // deg | cnt | fill block
        (size_t)N_NODES * 4 +               // invd
        (size_t)(N_NODES + 1) * 4 +         // rowptr
        (size_t)N_EDGES * 4 * 2 +           // edgeOf, dstp
        32768;
    int nc = 0, CSn = 0;
    size_t region_bytes = 0;
    for (int c = 2; c <= 16; c *= 2) {
        int csn = (((N_NODES + c - 1) / c) + 127) & ~127;
        size_t rb = (size_t)csn * NJ * 2;
        if (rb < eaBytes) rb = eaBytes;
        if (fixed + rb <= ws_size) { nc = c; CSn = csn; region_bytes = rb; break; }
    }
    if (nc == 0) {
        hipMemsetAsync(d_out, 0, (size_t)out_size * 4, stream);
        return;
    }

    char* ws = (char*)d_ws;
    size_t off = 0;
    auto alloc = [&](size_t bytes) {
        char* p = ws + off;
        off += (bytes + 255) & ~(size_t)255;
        return p;
    };
    unsigned short* region = (unsigned short*)alloc(region_bytes);
    unsigned short* y = region;
    unsigned short* eah = region;  // prep only (consumed by hgemm before first ygemm)
    unsigned short* hidp = (unsigned short*)alloc((size_t)(N_EDGES + 16) * HID * 2);
    unsigned short* w2h = (unsigned short*)alloc((size_t)NJ * NF * 2);
    unsigned short* w1h = (unsigned short*)alloc((size_t)HID * HID * 2);
    unsigned short* xh = (unsigned short*)alloc((size_t)M_PAD * NF * 2);
    float* xA = (float*)alloc((size_t)N_NODES * NF * 4);
    float* xB = (float*)alloc((size_t)N_NODES * NF * 4);
    float* agg = (float*)alloc((size_t)N_NODES * NF * 4);
    float* xb2 = (float*)alloc((size_t)N_NODES * NF * 4);
    char* degblk = alloc(3 * 40192);  // deg | cnt | fill (one memset)
    float* deg = (float*)degblk;
    int* cnt = (int*)(degblk + 40192);
    int* fill = (int*)(degblk + 2 * 40192);
    float* invd = (float*)alloc((size_t)N_NODES * 4);
    int* rowptr = (int*)alloc((size_t)(N_NODES + 1) * 4);
    int* edgeOf = (int*)alloc((size_t)N_EDGES * 4);
    int* dstp = (int*)alloc((size_t)N_EDGES * 4);

    // ---- prep: CSR by src + merged features/weights + hidden ----
    hipMemsetAsync(degblk, 0, 3 * 40192, stream);
    hipMemsetAsync(agg, 0, (size_t)N_NODES * NF * 4, stream);  // conv0's agg init
    hist_kernel<<<(N_EDGES + 255) / 256, 256, 0, stream>>>(srcIdx, dstIdx, deg, cnt);
    scan_kernel<<<1, 256, 0, stream>>>(cnt, deg, rowptr, invd);
    scatter_kernel<<<(N_EDGES + 255) / 256, 256, 0, stream>>>(srcIdx, dstIdx, rowptr, fill, edgeOf, dstp);
    prep_kernel<<<PREP_WPT, 256, 0, stream>>>(ea, edgeOf, eah,
                                              h, lin0_w, lin0_b, nn_b2, xA, xh, xb2,
                                              nn_w1, nn_w2, w1h, w2h);
    hgemm_kernel<<<N_EDGES / 128, 256, 0, stream>>>(eah, w1h, nn_b1, hidp);  // consumes ea region

    // ---- two conv applications (shared weights) ----
    for (int conv = 0; conv < 2; ++conv) {
        const float* xin = conv ? xB : xA;
        float* xout = conv ? (float*)d_out : xB;
        unsigned short* mh = conv ? nullptr : xh;

        for (int c = 0; c < nc; ++c) {
            int n0 = c * CSn;
            int n1 = n0 + CSn; if (n1 > N_NODES) n1 = N_NODES;
            if (n0 >= N_NODES) break;
            int gx = (n1 - n0 + 127) / 128;
            ygemm_kernel<<<dim3(gx, NJ / 256), 256, 0, stream>>>(xh, w2h, y, n0);
            matvec_mfma_kernel<<<(n1 - n0 + 3) / 4, 256, 0, stream>>>(y, hidp, rowptr, dstp,
                                                                      xb2, agg, n0, n1);
        }
        // combine reads agg and re-zeroes it for the next conv
        combine_kernel<<<N_NODES / 4, 256, 0, stream>>>(xin, agg, invd, root_w, conv_b, nn_b2,
                                                        xout, mh, xb2);
    }
}

// Round 19
// 332.726 us; speedup vs baseline: 1.0755x; 1.0303x over previous
//
#include <hip/hip_runtime.h>

#define N_NODES 10000
#define N_EDGES 160000
#define HID 128
#define NG 100
#define NF 64
#define NIO 4096     // NF*NF (w2 row stride)
#define NJ 8192      // permuted columns: o(64) x k(128), o-major
#define M_PAD 10240  // padded x rows

// merged-prep block ranges
#define PREP_LIN0 2500                 // lin0: N_NODES/4
#define PREP_WPT (PREP_LIN0 + 2112)    // wpt: (HID*HID + NJ*NF)/256

typedef short bf16x8 __attribute__((ext_vector_type(8)));
typedef float f32x4 __attribute__((ext_vector_type(4)));

__device__ __forceinline__ unsigned short f2b(float f) {
    unsigned int u = __float_as_uint(f);
    u += 0x7fffu + ((u >> 16) & 1u);  // RNE
    return (unsigned short)(u >> 16);
}
__device__ __forceinline__ float b2f(unsigned short s) { return __uint_as_float((unsigned int)s << 16); }

// fragment-major index: element (row, k) of a K=64 operand, panel stride 1024
__device__ __forceinline__ long fidx64(int row, int k) {
    return (long)(row >> 4) * 1024 + (k >> 5) * 512 + ((((k >> 3) & 3) * 16 + (row & 15))) * 8 + (k & 7);
}
// K=128 operand, panel stride 2048
__device__ __forceinline__ long fidx128(int row, int k) {
    return (long)(row >> 4) * 2048 + (k >> 5) * 512 + ((((k >> 3) & 3) * 16 + (row & 15))) * 8 + (k & 7);
}

// ---------------- histograms (dst-degree for mean; src-count for CSR) ----------------
__global__ void hist_kernel(const int* __restrict__ src, const int* __restrict__ dst,
                            float* __restrict__ deg, int* __restrict__ cnt) {
    int e = blockIdx.x * 256 + threadIdx.x;
    if (e < N_EDGES) {
        atomicAdd(&deg[dst[e]], 1.0f);
        atomicAdd(&cnt[src[e]], 1);
    }
}

// ---------------- single-pass scan: rowptr = excl-prefix(cnt); invd = 1/max(deg,1) ----------------
#define SCAN_C 40  // 256 threads x 40 = 10240 >= N_NODES
__global__ void scan_kernel(const int* __restrict__ cnt, const float* __restrict__ deg,
                            int* __restrict__ rowptr, float* __restrict__ invd) {
    __shared__ int wsum[4];
    int t = threadIdx.x, wv = t >> 6, l = t & 63;
    int base_i = t * SCAN_C;
    int loc[SCAN_C];
    int sum = 0;
#pragma unroll
    for (int j = 0; j < SCAN_C; ++j) {
        int g = base_i + j;
        int v = (g < N_NODES) ? cnt[g] : 0;
        loc[j] = sum;  // exclusive prefix within thread
        sum += v;
    }
    int incl = sum;
    for (int off = 1; off < 64; off <<= 1) {
        int v = __shfl_up(incl, off);
        if (l >= off) incl += v;
    }
    if (l == 63) wsum[wv] = incl;
    __syncthreads();
    int wbase = 0;
#pragma unroll
    for (int w = 0; w < 4; ++w) wbase += (w < wv) ? wsum[w] : 0;
    int tbase = wbase + incl - sum;  // exclusive across block
#pragma unroll
    for (int j = 0; j < SCAN_C; ++j) {
        int g = base_i + j;
        if (g <= N_NODES) rowptr[g] = tbase + loc[j];
        if (g < N_NODES) invd[g] = 1.0f / fmaxf(deg[g], 1.0f);
    }
}

// ---------------- scatter: rankOf[e] (edge->rank), dstp[rank] ----------------
__global__ void scatter_kernel(const int* __restrict__ src, const int* __restrict__ dst,
                               const int* __restrict__ rowptr, int* __restrict__ fill,
                               int* __restrict__ rankOf, int* __restrict__ dstp) {
    int e = blockIdx.x * 256 + threadIdx.x;
    if (e < N_EDGES) {
        int s = src[e];
        int r = rowptr[s] + atomicAdd(&fill[s], 1);
        rankOf[e] = r;
        dstp[r] = dst[e];
    }
}

// ---------------- merged prep: lin0(+xb2) | weight permutes ----------------
__global__ void prep_kernel(const float* __restrict__ h, const float* __restrict__ lw,
                            const float* __restrict__ lb, const float* __restrict__ b2,
                            float* __restrict__ x, unsigned short* __restrict__ xh,
                            float* __restrict__ xb2,
                            const float* __restrict__ w1, const float* __restrict__ w2,
                            unsigned short* __restrict__ w1h, unsigned short* __restrict__ w2h) {
    int bid = blockIdx.x;
    if (bid < PREP_LIN0) {
        // ---- lin0: x0 = relu(h @ lin0_w + b); f32 + xh frag mirror + fused xb2 ----
        int wv = threadIdx.x >> 6, l = threadIdx.x & 63;
        int n = bid * 4 + wv;
        float h0 = h[n * HID + l];
        float h1 = h[n * HID + 64 + l];
        float acc = lb[l];
#pragma unroll
        for (int i = 0; i < 64; ++i) {
            acc += __shfl(h0, i) * lw[i * NF + l];
            acc += __shfl(h1, i) * lw[(64 + i) * NF + l];
        }
        float v = fmaxf(acc, 0.0f);
        x[n * NF + l] = v;
        xh[fidx64(n, l)] = f2b(v);
        float xb = 0.0f;
#pragma unroll
        for (int i = 0; i < 64; ++i) xb += __shfl(v, i) * b2[i * 64 + l];
        xb2[n * NF + l] = xb;
    } else {
        // ---- weight permutes: w1 (first 16384 ids) + w2 ----
        int id = (bid - PREP_LIN0) * 256 + threadIdx.x;
        if (id < HID * HID) {
            int k = id & 127, c = id >> 7;
            float v = (k < NG) ? w1[k * HID + c] : 0.0f;
            w1h[fidx128(c, k)] = f2b(v);
        } else {
            int id2 = id - HID * HID;  // id2 = j*64 + i
            int i = id2 & 63, j = id2 >> 6;
            int o = j >> 7, k = j & 127;  // j = o*128 + k
            w2h[fidx64(j, i)] = f2b(w2[k * NIO + i * 64 + o]);
        }
    }
}

// ---------------- hgemm: hid = relu(ea @ w1 + b1), ea read NATURALLY (stream), rank-scattered write ----
__launch_bounds__(256)
__global__ void hgemm_kernel(const float* __restrict__ ea, const int* __restrict__ rankOf,
                             const unsigned short* __restrict__ w1h,
                             const float* __restrict__ b1, unsigned short* __restrict__ hidp) {
    __shared__ float stg[4][1056];
    const int tid = threadIdx.x, wv = tid >> 6, l = tid & 63;
    const long grow = (long)blockIdx.x * 128;  // edge-natural tile base
    const int wr = (wv >> 1) * 64, wc = (wv & 1) * 64;
    const long bpan0 = (wc >> 4);
    const int lc = l & 15, lk = l >> 4;

    f32x4 acc[4][4] = {};
#pragma unroll
    for (int ks = 0; ks < 4; ++ks) {
        const int c0 = ks * 32 + lk * 8;  // in {0,8,...,120}
        bf16x8 a[4], b[4];
#pragma unroll
        for (int m = 0; m < 4; ++m) {
            const float* Ar = ea + (grow + wr + m * 16 + lc) * (long)NG;
            f32x4 lo = {0.0f, 0.0f, 0.0f, 0.0f}, hi = {0.0f, 0.0f, 0.0f, 0.0f};
            if (c0 <= 88) {
                lo = *(const f32x4*)(Ar + c0);
                hi = *(const f32x4*)(Ar + c0 + 4);
            } else if (c0 == 96) {
                lo = *(const f32x4*)(Ar + 96);  // 96..99 valid, rest zero-pad
            }
            bf16x8 t;
            t[0] = f2b(lo[0]); t[1] = f2b(lo[1]); t[2] = f2b(lo[2]); t[3] = f2b(lo[3]);
            t[4] = f2b(hi[0]); t[5] = f2b(hi[1]); t[6] = f2b(hi[2]); t[7] = f2b(hi[3]);
            a[m] = t;
        }
#pragma unroll
        for (int n = 0; n < 4; ++n)
            b[n] = *(const bf16x8*)(w1h + (bpan0 + n) * 2048 + ks * 512 + (long)l * 8);
#pragma unroll
        for (int m = 0; m < 4; ++m)
#pragma unroll
            for (int n = 0; n < 4; ++n)
                acc[m][n] = __builtin_amdgcn_mfma_f32_16x16x32_bf16(a[m], b[n], acc[m][n], 0, 0, 0);
    }

    float* s = stg[wv];
    int r8 = l >> 3, cg = l & 7;
#pragma unroll
    for (int m = 0; m < 4; ++m) {
#pragma unroll
        for (int n = 0; n < 4; ++n)
#pragma unroll
            for (int q = 0; q < 4; ++q)
                s[((l >> 4) * 4 + q) * 66 + n * 16 + (l & 15)] = acc[m][n][q];
#pragma unroll
        for (int it = 0; it < 2; ++it) {
            int row = it * 8 + r8;
            const float* sr = s + row * 66 + cg * 8;
            int colbase = wc + cg * 8;
            unsigned int u[4];
#pragma unroll
            for (int p = 0; p < 4; ++p) {
                float f0 = fmaxf(sr[2 * p] + b1[colbase + 2 * p], 0.0f);
                float f1 = fmaxf(sr[2 * p + 1] + b1[colbase + 2 * p + 1], 0.0f);
                u[p] = ((unsigned int)f2b(f1) << 16) | f2b(f0);
            }
            long Redge = grow + wr + m * 16 + row;          // natural edge index
            long Ro = rankOf[Redge];                        // rank slot (scattered full-row write)
            *(uint4*)(hidp + Ro * HID + colbase) = make_uint4(u[0], u[1], u[2], u[3]);
        }
    }
}

// ---------------- ygemm: single-pass bf16, 2 col-tiles per block (A-frag reuse) ----------------
__launch_bounds__(256)
__global__ void ygemm_kernel(const unsigned short* __restrict__ xh,
                             const unsigned short* __restrict__ wh,
                             unsigned short* __restrict__ y, int n0) {
    __shared__ float stg[4][1056];
    const int tid = threadIdx.x, wv = tid >> 6, l = tid & 63;
    const int grow = blockIdx.x * 128;
    const int col0base = blockIdx.y * 256;  // 2 x 128-col tiles
    const int wr = (wv >> 1) * 64, wc = (wv & 1) * 64;
    const long apan0 = ((n0 + grow + wr) >> 4);
    const int r8 = l >> 3, cg = l & 7;

    // A-fragments loaded once, reused across both col-tiles
    bf16x8 a[2][4];
#pragma unroll
    for (int ks = 0; ks < 2; ++ks)
#pragma unroll
        for (int m = 0; m < 4; ++m)
            a[ks][m] = *(const bf16x8*)(xh + (apan0 + m) * 1024 + ks * 512 + (long)l * 8);

    for (int ct = 0; ct < 2; ++ct) {
        const int col0 = col0base + ct * 128;
        const long bpan0 = ((col0 + wc) >> 4);
        f32x4 acc[4][4] = {};
#pragma unroll
        for (int ks = 0; ks < 2; ++ks) {
            bf16x8 b[4];
#pragma unroll
            for (int n = 0; n < 4; ++n)
                b[n] = *(const bf16x8*)(wh + (bpan0 + n) * 1024 + ks * 512 + (long)l * 8);
#pragma unroll
            for (int m = 0; m < 4; ++m)
#pragma unroll
                for (int n = 0; n < 4; ++n)
                    acc[m][n] = __builtin_amdgcn_mfma_f32_16x16x32_bf16(a[ks][m], b[n], acc[m][n], 0, 0, 0);
        }

        float* s = stg[wv];
#pragma unroll
        for (int m = 0; m < 4; ++m) {
#pragma unroll
            for (int n = 0; n < 4; ++n)
#pragma unroll
                for (int q = 0; q < 4; ++q)
                    s[((l >> 4) * 4 + q) * 66 + n * 16 + (l & 15)] = acc[m][n][q];
            // wave-private staging: same-wave ds_write -> ds_read ordered via lgkmcnt
#pragma unroll
            for (int it = 0; it < 2; ++it) {
                int row = it * 8 + r8;
                const float* sr = s + row * 66 + cg * 8;
                unsigned int u[4];
#pragma unroll
                for (int p = 0; p < 4; ++p)
                    u[p] = ((unsigned int)f2b(sr[2 * p + 1]) << 16) | f2b(sr[2 * p]);
                long R = grow + wr + m * 16 + row;
                *(uint4*)(y + R * NJ + col0 + wc + cg * 8) = make_uint4(u[0], u[1], u[2], u[3]);
            }
        }
    }
}

// ---------------- matvec: ONE WAVE PER NODE (all 64 o), atomic scatter into agg ----------------
__global__ void matvec_mfma_kernel(const unsigned short* __restrict__ y,
                                   const unsigned short* __restrict__ hidp,
                                   const int* __restrict__ rowptr, const int* __restrict__ dstp,
                                   const float* __restrict__ xb2, float* __restrict__ agg,
                                   int n0, int n1) {
    int wv = threadIdx.x >> 6, l = threadIdx.x & 63;
    int s = n0 + blockIdx.x * 4 + wv;
    if (s >= n1) return;
    int r0 = rowptr[s], r1 = rowptr[s + 1];
    if (r0 == r1) return;
    int lc = l & 15, lk = l >> 4;

    // B-fragments for all 4 o-groups: y[s] is o-major [o][k], k contiguous
    const unsigned short* Ys = y + (long)(s - n0) * NJ;
    bf16x8 b[4][4];
    float xb2v[4];
#pragma unroll
    for (int og = 0; og < 4; ++og) {
        const unsigned short* Yo = Ys + (og * 16 + lc) * HID + lk * 8;
#pragma unroll
        for (int ks = 0; ks < 4; ++ks) b[og][ks] = *(const bf16x8*)(Yo + ks * 32);
        xb2v[og] = xb2[(long)s * NF + og * 16 + lc];
    }

    for (int mt = r0; mt < r1; mt += 16) {
        const unsigned short* Hs = hidp + (long)(mt + lc) * HID + lk * 8;
        bf16x8 a[4];
#pragma unroll
        for (int ks = 0; ks < 4; ++ks) a[ks] = *(const bf16x8*)(Hs + ks * 32);  // shared across og
        f32x4 acc[4] = {};
#pragma unroll
        for (int og = 0; og < 4; ++og)
#pragma unroll
            for (int ks = 0; ks < 4; ++ks)
                acc[og] = __builtin_amdgcn_mfma_f32_16x16x32_bf16(a[ks], b[og][ks], acc[og], 0, 0, 0);
#pragma unroll
        for (int q = 0; q < 4; ++q) {
            int rank = mt + lk * 4 + q;
            if (rank < r1) {
                long base = (long)dstp[rank] * NF;
#pragma unroll
                for (int og = 0; og < 4; ++og)
                    atomicAdd(&agg[base + og * 16 + lc], acc[og][q] + xb2v[og]);
            }
        }
    }
}

// ---------------- combine: agg*inv_deg + x @ root_w + conv_b; zeroes agg for next conv ----------------
__global__ void combine_kernel(const float* __restrict__ x, float* __restrict__ agg,
                               const float* __restrict__ invd, const float* __restrict__ rw,
                               const float* __restrict__ cb, const float* __restrict__ b2,
                               float* __restrict__ xo, unsigned short* __restrict__ xh,
                               float* __restrict__ xb2) {
    int wv = threadIdx.x >> 6, l = threadIdx.x & 63;
    int n = blockIdx.x * 4 + wv;
    float xv = x[n * NF + l];
    float acc = cb[l];
#pragma unroll
    for (int i = 0; i < 64; ++i) acc += __shfl(xv, i) * rw[i * NF + l];
    float av = agg[n * NF + l];
    agg[n * NF + l] = 0.0f;  // re-zero for next conv (replay-safe: prep memset covers conv0)
    float v = av * invd[n] + acc;
    xo[n * NF + l] = v;
    if (xh) {
        xh[fidx64(n, l)] = f2b(v);
        float xb = 0.0f;
#pragma unroll
        for (int i = 0; i < 64; ++i) xb += __shfl(v, i) * b2[i * 64 + l];
        xb2[n * NF + l] = xb;
    }
}

extern "C" void kernel_launch(void* const* d_in, const int* in_sizes, int n_in,
                              void* d_out, int out_size, void* d_ws, size_t ws_size,
                              hipStream_t stream) {
    const float* h = (const float*)d_in[0];
    const int* ei = (const int*)d_in[1];
    const float* ea = (const float*)d_in[3];
    const float* lin0_w = (const float*)d_in[5];
    const float* lin0_b = (const float*)d_in[6];
    const float* nn_w1 = (const float*)d_in[7];
    const float* nn_b1 = (const float*)d_in[8];
    const float* nn_w2 = (const float*)d_in[9];
    const float* nn_b2 = (const float*)d_in[10];
    const float* root_w = (const float*)d_in[11];
    const float* conv_b = (const float*)d_in[12];
    const int* srcIdx = ei;
    const int* dstIdx = ei + N_EDGES;

    // ---- tier selection: start at nc=2 so the y chunk (~84MB) stays LLC-resident ----
    const size_t fixed =
        (size_t)(N_EDGES + 16) * HID * 2 +  // hidp
        (size_t)NJ * NF * 2 +               // w2h
        (size_t)HID * HID * 2 +             // w1h
        (size_t)M_PAD * NF * 2 +            // xh mirror
        (size_t)N_NODES * NF * 4 * 4 +      // xA, xB, agg, xb2
        3 * 40192 +                         // deg | cnt | fill block
        (size_t)N_NODES * 4 +               // invd
        (size_t)(N_NODES + 1) * 4 +         // rowptr
        (size_t)N_EDGES * 4 * 2 +           // rankOf, dstp
        32768;
    int nc = 0, CSn = 0;
    size_t region_bytes = 0;
    for (int c = 2; c <= 16; c *= 2) {
        int csn = (((N_NODES + c - 1) / c) + 127) & ~127;
        size_t rb = (size_t)csn * NJ * 2;
        if (fixed + rb <= ws_size) { nc = c; CSn = csn; region_bytes = rb; break; }
    }
    if (nc == 0) {
        hipMemsetAsync(d_out, 0, (size_t)out_size * 4, stream);
        return;
    }

    char* ws = (char*)d_ws;
    size_t off = 0;
    auto alloc = [&](size_t bytes) {
        char* p = ws + off;
        off += (bytes + 255) & ~(size_t)255;
        return p;
    };
    unsigned short* y = (unsigned short*)alloc(region_bytes);
    unsigned short* hidp = (unsigned short*)alloc((size_t)(N_EDGES + 16) * HID * 2);
    unsigned short* w2h = (unsigned short*)alloc((size_t)NJ * NF * 2);
    unsigned short* w1h = (unsigned short*)alloc((size_t)HID * HID * 2);
    unsigned short* xh = (unsigned short*)alloc((size_t)M_PAD * NF * 2);
    float* xA = (float*)alloc((size_t)N_NODES * NF * 4);
    float* xB = (float*)alloc((size_t)N_NODES * NF * 4);
    float* agg = (float*)alloc((size_t)N_NODES * NF * 4);
    float* xb2 = (float*)alloc((size_t)N_NODES * NF * 4);
    char* degblk = alloc(3 * 40192);  // deg | cnt | fill (one memset)
    float* deg = (float*)degblk;
    int* cnt = (int*)(degblk + 40192);
    int* fill = (int*)(degblk + 2 * 40192);
    float* invd = (float*)alloc((size_t)N_NODES * 4);
    int* rowptr = (int*)alloc((size_t)(N_NODES + 1) * 4);
    int* rankOf = (int*)alloc((size_t)N_EDGES * 4);
    int* dstp = (int*)alloc((size_t)N_EDGES * 4);

    // ---- prep: CSR by src + features/weights + hidden (direct-stream hgemm) ----
    hipMemsetAsync(degblk, 0, 3 * 40192, stream);
    hipMemsetAsync(agg, 0, (size_t)N_NODES * NF * 4, stream);  // conv0's agg init
    hist_kernel<<<(N_EDGES + 255) / 256, 256, 0, stream>>>(srcIdx, dstIdx, deg, cnt);
    scan_kernel<<<1, 256, 0, stream>>>(cnt, deg, rowptr, invd);
    scatter_kernel<<<(N_EDGES + 255) / 256, 256, 0, stream>>>(srcIdx, dstIdx, rowptr, fill, rankOf, dstp);
    prep_kernel<<<PREP_WPT, 256, 0, stream>>>(h, lin0_w, lin0_b, nn_b2, xA, xh, xb2,
                                              nn_w1, nn_w2, w1h, w2h);
    hgemm_kernel<<<N_EDGES / 128, 256, 0, stream>>>(ea, rankOf, w1h, nn_b1, hidp);

    // ---- two conv applications (shared weights) ----
    for (int conv = 0; conv < 2; ++conv) {
        const float* xin = conv ? xB : xA;
        float* xout = conv ? (float*)d_out : xB;
        unsigned short* mh = conv ? nullptr : xh;

        for (int c = 0; c < nc; ++c) {
            int n0 = c * CSn;
            int n1 = n0 + CSn; if (n1 > N_NODES) n1 = N_NODES;
            if (n0 >= N_NODES) break;
            int gx = (n1 - n0 + 127) / 128;
            ygemm_kernel<<<dim3(gx, NJ / 256), 256, 0, stream>>>(xh, w2h, y, n0);
            matvec_mfma_kernel<<<(n1 - n0 + 3) / 4, 256, 0, stream>>>(y, hidp, rowptr, dstp,
                                                                      xb2, agg, n0, n1);
        }
        // combine reads agg and re-zeroes it for the next conv
        combine_kernel<<<N_NODES / 4, 256, 0, stream>>>(xin, agg, invd, root_w, conv_b, nn_b2,
                                                        xout, mh, xb2);
    }
}